// Round 6
// baseline (278.755 us; speedup 1.0000x reference)
//
#include <hip/hip_runtime.h>
#include <hip/hip_bf16.h>
#include <math.h>

#define N_NODES 100000
#define E_EDGES 1600000
#define IN_F 256
#define OUT_F 128
#define LRELU_ALPHA 0.2f

typedef __attribute__((ext_vector_type(8))) short bf16x8;
typedef __attribute__((ext_vector_type(4))) float f32x4;

__device__ __forceinline__ unsigned short f32_to_bf16(float f) {
  unsigned int u = __float_as_uint(f);
  u = (u + 0x7fffu + ((u >> 16) & 1u)) >> 16;  // round-to-nearest-even
  return (unsigned short)u;
}
// packed fp32x2 -> bf16x2 (low = a, high = b); uses v_cvt_pk_bf16_f32 on gfx950
__device__ __forceinline__ unsigned cvt2(float a, float b) {
  __hip_bfloat162 v = __float22bfloat162_rn(make_float2(a, b));
  unsigned u;
  __builtin_memcpy(&u, &v, 4);
  return u;
}
__device__ __forceinline__ float elu1(float x) {
  return x > 0.f ? x : __expf(x) - 1.f;
}

// ---------------------------------------------------------------------------
// Prep: blocks [0,390]: row_ptr binary search; blocks [391,518]:
// Wt16[n][k] = bf16(W[k][n]).
// ---------------------------------------------------------------------------
#define ROWPTR_BLOCKS 391
__global__ void prep_kernel(const int* __restrict__ row,
                            int* __restrict__ row_ptr,
                            const float* __restrict__ W,
                            unsigned short* __restrict__ Wt16) {
  const int b = blockIdx.x;
  if (b < ROWPTR_BLOCKS) {
    const int i = b * 256 + threadIdx.x;
    if (i > N_NODES) return;
    int lo = 0, hi = E_EDGES;
    while (lo < hi) {
      const int mid = (lo + hi) >> 1;
      if (row[mid] < i) lo = mid + 1; else hi = mid;
    }
    row_ptr[i] = lo;
  } else {
    const int idx = (b - ROWPTR_BLOCKS) * 256 + threadIdx.x;  // 0..32767
    const int n = idx >> 8;
    const int k = idx & 255;
    Wt16[n * IN_F + k] = f32_to_bf16(W[k * OUT_F + n]);
  }
}

// ---------------------------------------------------------------------------
// Kernel 1: Wh16 = bf16(h @ W) via MFMA 16x16x32_bf16.
// R6 rewrite: NO LDS, NO BARRIERS in the K-loop. Both operands are loaded
// directly into MFMA fragment layout: A from h (each row's 128 B k-slice is
// fully consumed by the 4 quads — no fetch waste), B from Wt16 (64 KB total,
// L2/L3-resident by construction; ~200 MB of L2 re-reads ≈ 6 µs at 34.5
// TB/s). Full unroll over 8 K-tiles exposes ~48 independent global loads for
// compiler pipelining; occupancy is VGPR-limited, not LDS-limited (LDS is
// only the 18.4 KB epilogue scratch, one barrier per kernel).
// R2's failure mode (2 blocks/CU from 68 KB LDS + 800 K bank conflicts) is
// structurally absent here.
// ---------------------------------------------------------------------------
#define OS_STRIDE 136
__global__ __launch_bounds__(256) void gemm_mfma(
    const float* __restrict__ h, const unsigned short* __restrict__ Wt16,
    const float* __restrict__ a_src, const float* __restrict__ a_dst,
    unsigned short* __restrict__ Wh16, float* __restrict__ f1,
    float* __restrict__ f2) {
  __shared__ unsigned short cst[64 * OS_STRIDE];  // 17408 B (C staging)
  __shared__ float fredp[256];                    // 1024 B (f1/f2 reduce)

  const int tid = threadIdx.x;
  const int lane = tid & 63;
  const int w = tid >> 6;        // wave 0..3
  const int wr = w >> 1;         // wave row 0..1 (x32 rows)
  const int wc = w & 1;          // wave col 0..1 (x64 cols)
  const int quad = lane >> 4;    // 0..3
  const int lm = lane & 15;      // m/n within tile
  const int m0 = blockIdx.x * 64;

  f32x4 acc[2][4];
#pragma unroll
  for (int a = 0; a < 2; ++a)
#pragma unroll
    for (int b = 0; b < 4; ++b) acc[a][b] = (f32x4){0.f, 0.f, 0.f, 0.f};

  // fragment base pointers (per-lane)
  const float* hA[2];
#pragma unroll
  for (int t = 0; t < 2; ++t) {
    const int r = min(m0 + wr * 32 + t * 16 + lm, N_NODES - 1);  // tail clamp
    hA[t] = h + (size_t)r * IN_F + quad * 8;
  }
  const unsigned short* Bp[4];
#pragma unroll
  for (int tc = 0; tc < 4; ++tc) {
    const int n = wc * 64 + tc * 16 + lm;
    Bp[tc] = Wt16 + n * IN_F + quad * 8;
  }

#pragma unroll
  for (int kt = 0; kt < 8; ++kt) {
    const int k0 = kt * 32;
    bf16x8 af[2], bfr[4];
#pragma unroll
    for (int t = 0; t < 2; ++t) {
      const float4 u0 = *reinterpret_cast<const float4*>(hA[t] + k0);
      const float4 u1 = *reinterpret_cast<const float4*>(hA[t] + k0 + 4);
      uint4 pk;
      pk.x = cvt2(u0.x, u0.y); pk.y = cvt2(u0.z, u0.w);
      pk.z = cvt2(u1.x, u1.y); pk.w = cvt2(u1.z, u1.w);
      af[t] = *reinterpret_cast<bf16x8*>(&pk);
    }
#pragma unroll
    for (int tc = 0; tc < 4; ++tc)
      bfr[tc] = *reinterpret_cast<const bf16x8*>(Bp[tc] + k0);
#pragma unroll
    for (int tr = 0; tr < 2; ++tr)
#pragma unroll
      for (int tc = 0; tc < 4; ++tc)
        acc[tr][tc] = __builtin_amdgcn_mfma_f32_16x16x32_bf16(
            af[tr], bfr[tc], acc[tr][tc], 0, 0, 0);
  }

  // ---- epilogue 1: f1/f2 partials (per-wave disjoint rows), no atomics
  float asv[4], adv[4];
#pragma unroll
  for (int tc = 0; tc < 4; ++tc) {
    asv[tc] = a_src[wc * 64 + tc * 16 + lm];
    adv[tc] = a_dst[wc * 64 + tc * 16 + lm];
  }
#pragma unroll
  for (int tr = 0; tr < 2; ++tr) {
#pragma unroll
    for (int reg = 0; reg < 4; ++reg) {
      float p1 = 0.f, p2 = 0.f;
#pragma unroll
      for (int tc = 0; tc < 4; ++tc) {
        p1 = fmaf(acc[tr][tc][reg], asv[tc], p1);
        p2 = fmaf(acc[tr][tc][reg], adv[tc], p2);
      }
#pragma unroll
      for (int o = 1; o < 16; o <<= 1) {  // reduce the 16 lm lanes
        p1 += __shfl_xor(p1, o);
        p2 += __shfl_xor(p2, o);
      }
      if (lm == 0) {
        const int r = wr * 32 + tr * 16 + quad * 4 + reg;  // 0..63
        fredp[wc * 128 + r * 2 + 0] = p1;
        fredp[wc * 128 + r * 2 + 1] = p2;
      }
    }
  }

  // ---- epilogue 2: stage C tile (bf16) to LDS, combine f1/f2 halves
#pragma unroll
  for (int tr = 0; tr < 2; ++tr)
#pragma unroll
    for (int tc = 0; tc < 4; ++tc)
#pragma unroll
      for (int reg = 0; reg < 4; ++reg)
        cst[(wr * 32 + tr * 16 + quad * 4 + reg) * OS_STRIDE + wc * 64 +
            tc * 16 + lm] = f32_to_bf16(acc[tr][tc][reg]);
  __syncthreads();  // the kernel's only barrier
  if (tid < 64 && m0 + tid < N_NODES) {
    f1[m0 + tid] = fredp[tid * 2 + 0] + fredp[128 + tid * 2 + 0];
    f2[m0 + tid] = fredp[tid * 2 + 1] + fredp[128 + tid * 2 + 1];
  }
  // copy-out: thread t -> row t/4 (0..63), quarter t&3 (64 B = 4 uint4)
  {
    const int rr = tid >> 2, part = tid & 3;
    if (m0 + rr < N_NODES) {
      uint4* dst =
          reinterpret_cast<uint4*>(&Wh16[(m0 + rr) * OUT_F + part * 32]);
      const uint4* src =
          reinterpret_cast<const uint4*>(&cst[rr * OS_STRIDE + part * 32]);
#pragma unroll
      for (int i = 0; i < 4; ++i) dst[i] = src[i];
    }
  }
}

// ---------------------------------------------------------------------------
// Kernel 2: segment softmax + SpMM + ELU. One wave per node, 4 nodes/block.
// v7 (unchanged — best of v5/v6/v7; declared locally converged at ~65 µs,
// mixed HBM(47%)+VALU(62%) regime on irreducible random-gather traffic).
// ---------------------------------------------------------------------------
__global__ __launch_bounds__(256) void gat_v7(
    const unsigned int* __restrict__ Whu,  // Wh16 viewed as dwords [N][64]
    const float* __restrict__ f1, const float* __restrict__ f2,
    const int* __restrict__ row_ptr, const int* __restrict__ col,
    float* __restrict__ out) {
  __shared__ int2 edge_s[4][128];

  const int w = threadIdx.x >> 6;
  const int lane = threadIdx.x & 63;
  const int node = blockIdx.x * 4 + w;

  const int start = row_ptr[node];
  const int deg = row_ptr[node + 1] - start;
  float2* outp = reinterpret_cast<float2*>(&out[node * OUT_F + lane * 2]);

  if (deg == 0) {
    *outp = make_float2(0.f, 0.f);
    return;
  }
  const float f1i = f1[node];
  float acc0 = 0.f, acc1 = 0.f, s = 0.f, inv;

  if (deg <= 128) {
    // fused pass: logits -> exp -> LDS, running sum (no max subtraction:
    // logits are ~N(0,1.6^2), fp32-safe, exact-math identical to reference)
    for (int idx = lane; idx < deg; idx += 64) {
      const int c = col[start + idx];
      float v = f1i + f2[c];
      v = fmaxf(v, LRELU_ALPHA * v);  // leaky-relu, alpha < 1
      const float x = __expf(v);
      edge_s[w][idx] = make_int2(__float_as_int(x), c << 6);  // c*64 dword idx
      s += x;
    }
#pragma unroll
    for (int o = 32; o > 0; o >>= 1) s += __shfl_xor(s, o);
    inv = 1.f / s;
    __builtin_amdgcn_wave_barrier();
    // pad to multiple of 16 with zero-contribution entries (att=0, col=0)
    const int padded = (deg + 15) & ~15;
    if (lane < padded - deg)
      edge_s[w][deg + lane] = make_int2(0, 0);  // 0.0f bits, row 0 (L2-hot)
    __builtin_amdgcn_wave_barrier();
    // pass C: guard-free, 16 edges per iteration, 16 gathers in flight
    for (int j = 0; j < padded; j += 16) {
      int2 e[16];
#pragma unroll
      for (int u = 0; u < 16; ++u) e[u] = edge_s[w][j + u];
      unsigned g[16];
#pragma unroll
      for (int u = 0; u < 16; ++u) g[u] = Whu[e[u].y + lane];
#pragma unroll
      for (int u = 0; u < 16; ++u) {
        const float a = __int_as_float(e[u].x);
        acc0 = fmaf(a, __uint_as_float(g[u] << 16), acc0);
        acc1 = fmaf(a, __uint_as_float(g[u] & 0xffff0000u), acc1);
      }
    }
  } else {
    // slow path (deg > 128, ~never at mean degree 16): 3-pass recompute,
    // keeps max-subtraction for safety.
    float m = -INFINITY;
    for (int idx = lane; idx < deg; idx += 64) {
      float v = f1i + f2[col[start + idx]];
      v = fmaxf(v, LRELU_ALPHA * v);
      m = fmaxf(m, v);
    }
#pragma unroll
    for (int o = 32; o > 0; o >>= 1) m = fmaxf(m, __shfl_xor(m, o));
    for (int idx = lane; idx < deg; idx += 64) {
      float v = f1i + f2[col[start + idx]];
      v = fmaxf(v, LRELU_ALPHA * v);
      s += __expf(v - m);
    }
#pragma unroll
    for (int o = 32; o > 0; o >>= 1) s += __shfl_xor(s, o);
    inv = 1.f / s;
    for (int j = 0; j < deg; ++j) {
      const int c = col[start + j];
      float v = f1i + f2[c];
      v = fmaxf(v, LRELU_ALPHA * v);
      const float a = __expf(v - m);
      const unsigned g = Whu[c * 64 + lane];
      acc0 = fmaf(a, __uint_as_float(g << 16), acc0);
      acc1 = fmaf(a, __uint_as_float(g & 0xffff0000u), acc1);
    }
  }
  acc0 *= inv;
  acc1 *= inv;
  *outp = make_float2(elu1(acc0), elu1(acc1));
}

// ---------------------------------------------------------------------------
extern "C" void kernel_launch(void* const* d_in, const int* in_sizes, int n_in,
                              void* d_out, int out_size, void* d_ws,
                              size_t ws_size, hipStream_t stream) {
  const float* h     = (const float*)d_in[0];
  const float* W     = (const float*)d_in[1];
  const float* a_src = (const float*)d_in[2];
  const float* a_dst = (const float*)d_in[3];
  const int*   row   = (const int*)d_in[4];
  const int*   col   = (const int*)d_in[5];
  float* out = (float*)d_out;

  char* ws = (char*)d_ws;
  unsigned short* Wh16 = (unsigned short*)(ws);        // N*128*2 = 25,600,000 B
  float* f1      = (float*)(ws + 25600000);            //    400,000 B
  float* f2      = (float*)(ws + 26000000);            //    400,000 B
  int*   row_ptr = (int*)  (ws + 26400000);            //    400,004 B
  unsigned short* Wt16 = (unsigned short*)(ws + 26800016);  // 64 KB, align16

  hipLaunchKernelGGL(prep_kernel, dim3(ROWPTR_BLOCKS + 128), dim3(256), 0,
                     stream, row, row_ptr, W, Wt16);
  hipLaunchKernelGGL(gemm_mfma, dim3((N_NODES + 63) / 64), dim3(256), 0,
                     stream, h, Wt16, a_src, a_dst, Wh16, f1, f2);
  hipLaunchKernelGGL(gat_v7, dim3(N_NODES / 4), dim3(256), 0, stream,
                     (const unsigned int*)Wh16, f1, f2, row_ptr, col, out);
}

// Round 7
// 256.430 us; speedup vs baseline: 1.0871x; 1.0871x over previous
//
#include <hip/hip_runtime.h>
#include <hip/hip_bf16.h>
#include <math.h>

#define N_NODES 100000
#define E_EDGES 1600000
#define IN_F 256
#define OUT_F 128
#define LRELU_ALPHA 0.2f

typedef __attribute__((ext_vector_type(8))) short bf16x8;
typedef __attribute__((ext_vector_type(4))) float f32x4;

__device__ __forceinline__ unsigned short f32_to_bf16(float f) {
  unsigned int u = __float_as_uint(f);
  u = (u + 0x7fffu + ((u >> 16) & 1u)) >> 16;  // round-to-nearest-even
  return (unsigned short)u;
}
// packed fp32x2 -> bf16x2 (low = a, high = b); uses v_cvt_pk_bf16_f32 on gfx950
__device__ __forceinline__ unsigned cvt2(float a, float b) {
  __hip_bfloat162 v = __float22bfloat162_rn(make_float2(a, b));
  unsigned u;
  __builtin_memcpy(&u, &v, 4);
  return u;
}
__device__ __forceinline__ float elu1(float x) {
  return x > 0.f ? x : __expf(x) - 1.f;
}

// fire-and-forget global -> LDS, 16 B per lane (dest = uniform base + lane*16)
typedef __attribute__((address_space(1))) const unsigned int gu32;
typedef __attribute__((address_space(3))) unsigned int lu32;
__device__ __forceinline__ void gll16(const void* g, void* l) {
  __builtin_amdgcn_global_load_lds((gu32*)g, (lu32*)l, 16, 0, 0);
}

// ---------------------------------------------------------------------------
// Prep: blocks [0,390]: row_ptr binary search; blocks [391,518]:
// Wt16[n][k] = bf16(W[k][n]).
// ---------------------------------------------------------------------------
#define ROWPTR_BLOCKS 391
__global__ void prep_kernel(const int* __restrict__ row,
                            int* __restrict__ row_ptr,
                            const float* __restrict__ W,
                            unsigned short* __restrict__ Wt16) {
  const int b = blockIdx.x;
  if (b < ROWPTR_BLOCKS) {
    const int i = b * 256 + threadIdx.x;
    if (i > N_NODES) return;
    int lo = 0, hi = E_EDGES;
    while (lo < hi) {
      const int mid = (lo + hi) >> 1;
      if (row[mid] < i) lo = mid + 1; else hi = mid;
    }
    row_ptr[i] = lo;
  } else {
    const int idx = (b - ROWPTR_BLOCKS) * 256 + threadIdx.x;  // 0..32767
    const int n = idx >> 8;
    const int k = idx & 255;
    Wt16[n * IN_F + k] = f32_to_bf16(W[k * OUT_F + n]);
  }
}

// ---------------------------------------------------------------------------
// Kernel 1: Wh16 = bf16(h @ W) via MFMA 16x16x32_bf16.
// R7: R4 skeleton (gll16 staging, M=64 tile, 1563 blocks, 32 KB LDS,
// 5 blocks/CU) + pipeline depth 2 with COUNTED vmcnt and raw barriers:
// prologue stages tiles 0,1; iter kt: vmcnt(4) [wait tile kt only, tile
// kt+1 stays in flight] -> s_barrier -> ds_read frags -> lgkmcnt(0) ->
// s_barrier -> stage tile kt+2 into the buffer just read -> MFMA.
// Each gll now has ~2 iteration bodies of latency cover instead of <1.
// Race audit: writes-before-reads = vmcnt+bar1 (everyone's tile-kt glls
// done); reads-before-overwrite = lgkmcnt+bar2 (everyone's buf[p] reads
// retired before any wave issues stage into buf[p]). kt=7 uses vmcnt(0).
// ---------------------------------------------------------------------------
#define OS_STRIDE 136
__global__ __launch_bounds__(256) void gemm_mfma(
    const float* __restrict__ h, const unsigned short* __restrict__ Wt16,
    const float* __restrict__ a_src, const float* __restrict__ a_dst,
    unsigned short* __restrict__ Wh16, float* __restrict__ f1,
    float* __restrict__ f2) {
  __shared__ unsigned short lds_us[16384];  // 32768 B
  char* ldsb = (char*)lds_us;

  const int tid = threadIdx.x;
  const int lane = tid & 63;
  const int w = tid >> 6;        // wave 0..3
  const int wr = w >> 1;         // wave row 0..1 (x32 rows)
  const int wc = w & 1;          // wave col 0..1 (x64 cols)
  const int quad = lane >> 4;    // 0..3
  const int lm = lane & 15;      // m/n within tile
  const int m0 = blockIdx.x * 64;

  f32x4 acc[2][4];
#pragma unroll
  for (int a = 0; a < 2; ++a)
#pragma unroll
    for (int b = 0; b < 4; ++b) acc[a][b] = (f32x4){0.f, 0.f, 0.f, 0.f};

  auto stage = [&](int p, int k0) {
    char* Ab = ldsb + p * 16384;
    char* Bb = Ab + 8192;
#pragma unroll
    for (int i = 0; i < 2; ++i) {
      const int r = 8 * (w + 4 * i) + (lane >> 3);
      const int gr = min(m0 + r, N_NODES - 1);  // tail clamp
      const float* src = h + (size_t)gr * IN_F + k0 + ((lane & 7) << 2);
      gll16(src, Ab + (w + 4 * i) * 1024);
    }
#pragma unroll
    for (int i = 0; i < 2; ++i) {
      const int n = 16 * (w + 4 * i) + (lane >> 2);
      const unsigned short* src = Wt16 + n * IN_F + k0 + ((lane & 3) << 3);
      gll16(src, Bb + (w + 4 * i) * 1024);
    }
  };

  // prologue: two tiles in flight
  stage(0, 0);
  stage(1, 32);

#pragma unroll
  for (int kt = 0; kt < 8; ++kt) {
    const int p = kt & 1;
    // wait for tile kt's glls (mine); tile kt+1's 4 glls stay in flight
    if (kt < 7) {
      asm volatile("s_waitcnt vmcnt(4)" ::: "memory");
    } else {
      asm volatile("s_waitcnt vmcnt(0)" ::: "memory");
    }
    __builtin_amdgcn_s_barrier();  // buf[p] fully staged by ALL waves

    const float* Af = (const float*)(ldsb + p * 16384);
    const unsigned short* Bf =
        (const unsigned short*)(ldsb + p * 16384 + 8192);
    bf16x8 af[2], bfr[4];
#pragma unroll
    for (int t = 0; t < 2; ++t) {
      const int r = wr * 32 + t * 16 + lm;
      const float4 u0 = *reinterpret_cast<const float4*>(Af + r * 32 + quad * 8);
      const float4 u1 =
          *reinterpret_cast<const float4*>(Af + r * 32 + quad * 8 + 4);
      uint4 pk;
      pk.x = cvt2(u0.x, u0.y); pk.y = cvt2(u0.z, u0.w);
      pk.z = cvt2(u1.x, u1.y); pk.w = cvt2(u1.z, u1.w);
      af[t] = *reinterpret_cast<bf16x8*>(&pk);
    }
#pragma unroll
    for (int tc = 0; tc < 4; ++tc) {
      const int n = wc * 64 + tc * 16 + lm;
      bfr[tc] = *reinterpret_cast<const bf16x8*>(Bf + n * 32 + quad * 8);
    }
    asm volatile("s_waitcnt lgkmcnt(0)" ::: "memory");  // my reads retired
    __builtin_amdgcn_sched_barrier(0);
    __builtin_amdgcn_s_barrier();  // ALL waves' reads of buf[p] retired

    if (kt < 6) stage(p, (kt + 2) * 32);  // overwrite buf[p], 2 tiles ahead

#pragma unroll
    for (int tr = 0; tr < 2; ++tr)
#pragma unroll
      for (int tc = 0; tc < 4; ++tc)
        acc[tr][tc] = __builtin_amdgcn_mfma_f32_16x16x32_bf16(
            af[tr], bfr[tc], acc[tr][tc], 0, 0, 0);
  }
  __syncthreads();  // all LDS use done; free for epilogue reuse

  // ---- epilogue 1: f1/f2 partials (per-wave disjoint rows), no atomics
  float* fredp = (float*)(ldsb + 17408);  // [wc][64 rows][2] = 256 floats
  float asv[4], adv[4];
#pragma unroll
  for (int tc = 0; tc < 4; ++tc) {
    asv[tc] = a_src[wc * 64 + tc * 16 + lm];
    adv[tc] = a_dst[wc * 64 + tc * 16 + lm];
  }
#pragma unroll
  for (int tr = 0; tr < 2; ++tr) {
#pragma unroll
    for (int reg = 0; reg < 4; ++reg) {
      float p1 = 0.f, p2 = 0.f;
#pragma unroll
      for (int tc = 0; tc < 4; ++tc) {
        p1 = fmaf(acc[tr][tc][reg], asv[tc], p1);
        p2 = fmaf(acc[tr][tc][reg], adv[tc], p2);
      }
#pragma unroll
      for (int o = 1; o < 16; o <<= 1) {  // reduce the 16 lm lanes
        p1 += __shfl_xor(p1, o);
        p2 += __shfl_xor(p2, o);
      }
      if (lm == 0) {
        const int r = wr * 32 + tr * 16 + quad * 4 + reg;  // 0..63
        fredp[wc * 128 + r * 2 + 0] = p1;
        fredp[wc * 128 + r * 2 + 1] = p2;
      }
    }
  }

  // ---- epilogue 2: stage C tile (bf16) to LDS, combine f1/f2 halves
#pragma unroll
  for (int tr = 0; tr < 2; ++tr)
#pragma unroll
    for (int tc = 0; tc < 4; ++tc)
#pragma unroll
      for (int reg = 0; reg < 4; ++reg)
        lds_us[(wr * 32 + tr * 16 + quad * 4 + reg) * OS_STRIDE + wc * 64 +
               tc * 16 + lm] = f32_to_bf16(acc[tr][tc][reg]);
  __syncthreads();
  if (tid < 64 && m0 + tid < N_NODES) {
    f1[m0 + tid] = fredp[tid * 2 + 0] + fredp[128 + tid * 2 + 0];
    f2[m0 + tid] = fredp[tid * 2 + 1] + fredp[128 + tid * 2 + 1];
  }
  // copy-out: thread t -> row t/4 (0..63), quarter t&3 (64 B = 4 uint4)
  {
    const int rr = tid >> 2, part = tid & 3;
    if (m0 + rr < N_NODES) {
      uint4* dst =
          reinterpret_cast<uint4*>(&Wh16[(m0 + rr) * OUT_F + part * 32]);
      const uint4* src =
          reinterpret_cast<const uint4*>(&lds_us[rr * OS_STRIDE + part * 32]);
#pragma unroll
      for (int i = 0; i < 4; ++i) dst[i] = src[i];
    }
  }
}

// ---------------------------------------------------------------------------
// Kernel 2: segment softmax + SpMM + ELU. One wave per node, 4 nodes/block.
// v7 (unchanged — best of v5/v6/v7; locally converged at ~65 µs, mixed
// HBM(47%)+VALU(62%) regime on irreducible random-gather traffic).
// ---------------------------------------------------------------------------
__global__ __launch_bounds__(256) void gat_v7(
    const unsigned int* __restrict__ Whu,  // Wh16 viewed as dwords [N][64]
    const float* __restrict__ f1, const float* __restrict__ f2,
    const int* __restrict__ row_ptr, const int* __restrict__ col,
    float* __restrict__ out) {
  __shared__ int2 edge_s[4][128];

  const int w = threadIdx.x >> 6;
  const int lane = threadIdx.x & 63;
  const int node = blockIdx.x * 4 + w;

  const int start = row_ptr[node];
  const int deg = row_ptr[node + 1] - start;
  float2* outp = reinterpret_cast<float2*>(&out[node * OUT_F + lane * 2]);

  if (deg == 0) {
    *outp = make_float2(0.f, 0.f);
    return;
  }
  const float f1i = f1[node];
  float acc0 = 0.f, acc1 = 0.f, s = 0.f, inv;

  if (deg <= 128) {
    // fused pass: logits -> exp -> LDS, running sum (no max subtraction:
    // logits are ~N(0,1.6^2), fp32-safe, exact-math identical to reference)
    for (int idx = lane; idx < deg; idx += 64) {
      const int c = col[start + idx];
      float v = f1i + f2[c];
      v = fmaxf(v, LRELU_ALPHA * v);  // leaky-relu, alpha < 1
      const float x = __expf(v);
      edge_s[w][idx] = make_int2(__float_as_int(x), c << 6);  // c*64 dword idx
      s += x;
    }
#pragma unroll
    for (int o = 32; o > 0; o >>= 1) s += __shfl_xor(s, o);
    inv = 1.f / s;
    __builtin_amdgcn_wave_barrier();
    // pad to multiple of 16 with zero-contribution entries (att=0, col=0)
    const int padded = (deg + 15) & ~15;
    if (lane < padded - deg)
      edge_s[w][deg + lane] = make_int2(0, 0);  // 0.0f bits, row 0 (L2-hot)
    __builtin_amdgcn_wave_barrier();
    // pass C: guard-free, 16 edges per iteration, 16 gathers in flight
    for (int j = 0; j < padded; j += 16) {
      int2 e[16];
#pragma unroll
      for (int u = 0; u < 16; ++u) e[u] = edge_s[w][j + u];
      unsigned g[16];
#pragma unroll
      for (int u = 0; u < 16; ++u) g[u] = Whu[e[u].y + lane];
#pragma unroll
      for (int u = 0; u < 16; ++u) {
        const float a = __int_as_float(e[u].x);
        acc0 = fmaf(a, __uint_as_float(g[u] << 16), acc0);
        acc1 = fmaf(a, __uint_as_float(g[u] & 0xffff0000u), acc1);
      }
    }
  } else {
    // slow path (deg > 128, ~never at mean degree 16): 3-pass recompute,
    // keeps max-subtraction for safety.
    float m = -INFINITY;
    for (int idx = lane; idx < deg; idx += 64) {
      float v = f1i + f2[col[start + idx]];
      v = fmaxf(v, LRELU_ALPHA * v);
      m = fmaxf(m, v);
    }
#pragma unroll
    for (int o = 32; o > 0; o >>= 1) m = fmaxf(m, __shfl_xor(m, o));
    for (int idx = lane; idx < deg; idx += 64) {
      float v = f1i + f2[col[start + idx]];
      v = fmaxf(v, LRELU_ALPHA * v);
      s += __expf(v - m);
    }
#pragma unroll
    for (int o = 32; o > 0; o >>= 1) s += __shfl_xor(s, o);
    inv = 1.f / s;
    for (int j = 0; j < deg; ++j) {
      const int c = col[start + j];
      float v = f1i + f2[c];
      v = fmaxf(v, LRELU_ALPHA * v);
      const float a = __expf(v - m);
      const unsigned g = Whu[c * 64 + lane];
      acc0 = fmaf(a, __uint_as_float(g << 16), acc0);
      acc1 = fmaf(a, __uint_as_float(g & 0xffff0000u), acc1);
    }
  }
  acc0 *= inv;
  acc1 *= inv;
  *outp = make_float2(elu1(acc0), elu1(acc1));
}

// ---------------------------------------------------------------------------
extern "C" void kernel_launch(void* const* d_in, const int* in_sizes, int n_in,
                              void* d_out, int out_size, void* d_ws,
                              size_t ws_size, hipStream_t stream) {
  const float* h     = (const float*)d_in[0];
  const float* W     = (const float*)d_in[1];
  const float* a_src = (const float*)d_in[2];
  const float* a_dst = (const float*)d_in[3];
  const int*   row   = (const int*)d_in[4];
  const int*   col   = (const int*)d_in[5];
  float* out = (float*)d_out;

  char* ws = (char*)d_ws;
  unsigned short* Wh16 = (unsigned short*)(ws);        // N*128*2 = 25,600,000 B
  float* f1      = (float*)(ws + 25600000);            //    400,000 B
  float* f2      = (float*)(ws + 26000000);            //    400,000 B
  int*   row_ptr = (int*)  (ws + 26400000);            //    400,004 B
  unsigned short* Wt16 = (unsigned short*)(ws + 26800016);  // 64 KB, align16

  hipLaunchKernelGGL(prep_kernel, dim3(ROWPTR_BLOCKS + 128), dim3(256), 0,
                     stream, row, row_ptr, W, Wt16);
  hipLaunchKernelGGL(gemm_mfma, dim3((N_NODES + 63) / 64), dim3(256), 0,
                     stream, h, Wt16, a_src, a_dst, Wh16, f1, f2);
  hipLaunchKernelGGL(gat_v7, dim3(N_NODES / 4), dim3(256), 0, stream,
                     (const unsigned int*)Wh16, f1, f2, row_ptr, col, out);
}